// Round 4
// baseline (516.580 us; speedup 1.0000x reference)
//
#include <hip/hip_runtime.h>

#define B_ 8
#define S_ 1025
#define D_ 768
#define H_ 12
#define KV_ 4
#define HD_ 64
#define NREP 3
#define SCALE_ 0.125f
#define EPS_ 1e-6f
#define SKP 1088   // padded key count (17*64)
#define SCS 1092   // LDS score row stride in floats
#define QBLK 8     // q-rows per block
#define NQT 129    // ceil(1025/8)

typedef __attribute__((ext_vector_type(8))) short bf16x8;
typedef __attribute__((ext_vector_type(4))) float f32x4;

__device__ __forceinline__ unsigned short f2bf(float f) {
  unsigned int u = __builtin_bit_cast(unsigned int, f);
  return (unsigned short)((u + 0x7FFFu + ((u >> 16) & 1u)) >> 16);
}
__device__ __forceinline__ unsigned int pk2(float a, float b) {
  return (unsigned int)f2bf(a) | ((unsigned int)f2bf(b) << 16);
}

// ---------------- casts ----------------
__global__ __launch_bounds__(256) void cast_x_kernel(const float* __restrict__ x,
                                                     unsigned short* __restrict__ xb, int n4) {
  int i = blockIdx.x * 256 + threadIdx.x;
  if (i >= n4) return;
  f32x4 v = *(const f32x4*)(x + (size_t)i * 4);
  uint2 o;
  o.x = pk2(v[0], v[1]);
  o.y = pk2(v[2], v[3]);
  *(uint2*)(xb + (size_t)i * 4) = o;
}

__global__ __launch_bounds__(256) void cast_wqkv_kernel(const float* __restrict__ Wq,
    const float* __restrict__ Wk, const float* __restrict__ Wv,
    unsigned short* __restrict__ WT) {
  int idx = blockIdx.x * 256 + threadIdx.x;  // = n*768 + k
  int n = idx / D_, k = idx % D_;
  float v;
  if (n < 768)       v = Wq[(size_t)k * 768 + n];
  else if (n < 1024) v = Wk[(size_t)k * 256 + (n - 768)];
  else               v = Wv[(size_t)k * 256 + (n - 1024)];
  WT[idx] = f2bf(v);
}

__global__ __launch_bounds__(256) void cast_wo_kernel(const float* __restrict__ Wo,
                                                      unsigned short* __restrict__ WT) {
  int idx = blockIdx.x * 256 + threadIdx.x;  // = n*768 + k
  int n = idx / D_, k = idx % D_;
  WT[idx] = f2bf(Wo[(size_t)k * D_ + n]);
}

// ---------------- GEMM: C[M][N] fp32 = A[M][K] bf16 @ BT[N][K] bf16 ----------------
#define BM 128
#define BN 128
#define BK 32
#define LSTR 40   // padded LDS row stride (ushorts)
__global__ __launch_bounds__(256) void gemm_bt(const unsigned short* __restrict__ A,
    const unsigned short* __restrict__ BT, float* __restrict__ C, int M, int N, int K) {
  __shared__ unsigned short As[BM * LSTR];
  __shared__ unsigned short Bs[BN * LSTR];
  const int nMt = (M + BM - 1) / BM;
  const int tm = blockIdx.x % nMt;
  const int tn = blockIdx.x / nMt;
  const int row0 = tm * BM, col0 = tn * BN;
  const int tid = threadIdx.x;
  const int l = tid & 63, w = tid >> 6;
  const int wr = (w >> 1) * 64, wc = (w & 1) * 64;
  const int lr = l & 15, lk = (l >> 4) * 8;
  f32x4 acc[4][4] = {};
  for (int kt = 0; kt < K; kt += BK) {
    __syncthreads();
#pragma unroll
    for (int i = 0; i < 2; ++i) {
      int c = tid + i * 256;
      int r = c >> 2;
      int ce = (c & 3) * 8;
      int gr = row0 + r; gr = gr < M ? gr : M - 1;
      bf16x8 va = *(const bf16x8*)(A + (size_t)gr * K + kt + ce);
      *(bf16x8*)&As[r * LSTR + ce] = va;
      bf16x8 vb = *(const bf16x8*)(BT + (size_t)(col0 + r) * K + kt + ce);
      *(bf16x8*)&Bs[r * LSTR + ce] = vb;
    }
    __syncthreads();
    bf16x8 af[4], bfr[4];
#pragma unroll
    for (int m = 0; m < 4; ++m)
      af[m] = *(const bf16x8*)&As[(wr + m * 16 + lr) * LSTR + lk];
#pragma unroll
    for (int n = 0; n < 4; ++n)
      bfr[n] = *(const bf16x8*)&Bs[(wc + n * 16 + lr) * LSTR + lk];
#pragma unroll
    for (int m = 0; m < 4; ++m)
#pragma unroll
      for (int n = 0; n < 4; ++n)
        acc[m][n] = __builtin_amdgcn_mfma_f32_16x16x32_bf16(af[m], bfr[n], acc[m][n], 0, 0, 0);
  }
  const int orow = (l >> 4) * 4;
#pragma unroll
  for (int m = 0; m < 4; ++m)
#pragma unroll
    for (int n = 0; n < 4; ++n)
#pragma unroll
      for (int r = 0; r < 4; ++r) {
        int row = row0 + wr + m * 16 + orow + r;
        int col = col0 + wc + n * 16 + lr;
        if (row < M) C[(size_t)row * N + col] = acc[m][n][r];
      }
}

// ---------------- QKV epilogue: rmsnorm + rope + layouts ----------------
__global__ __launch_bounds__(256) void qkv_epilogue(const float* __restrict__ QKV,
    const int* __restrict__ pos_ids, const int* __restrict__ ghp, const int* __restrict__ gwp,
    const float* __restrict__ qw, const float* __restrict__ kw,
    unsigned short* __restrict__ Qb, unsigned short* __restrict__ Kb,
    unsigned short* __restrict__ Vt) {
  int tok = blockIdx.x * 4 + (threadIdx.x >> 6);
  int l = threadIdx.x & 63;
  if (tok >= B_ * S_) return;
  int b = tok / S_, s = tok % S_;
  const float* rowp = QKV + (size_t)tok * 1280;
  bool rot = (s > 0);
  float cs = 1.f, sn = 0.f;
  if (rot) {
    int gh = ghp[0], gw = gwp[0];
    int pos = pos_ids[tok];
    int hi = (pos / gw) % gh;
    int wi = pos % gw;
    int pi = l >> 1;
    int j = pi < 16 ? pi : pi - 16;
    float invf = exp2f(-(float)j * (13.287712379549449f / 16.f)); // 10000^(-j/16)
    float ang = (pi < 16 ? (float)hi : (float)wi) * invf;
    cs = cosf(ang); sn = sinf(ang);
  }
#pragma unroll
  for (int h = 0; h < H_; ++h) {
    float x = rowp[h * 64 + l];
    float ss = x * x;
    for (int off = 32; off; off >>= 1) ss += __shfl_xor(ss, off);
    float xn = x * rsqrtf(ss * (1.f / 64.f) + EPS_) * qw[l];
    float o = xn;
    if (rot) {
      float p = __shfl_xor(xn, 1);
      o = (l & 1) ? (p * sn + xn * cs) : (xn * cs - p * sn);
    }
    o *= SCALE_;
    Qb[((size_t)(b * H_ + h) * S_ + s) * 64 + l] = f2bf(o);
  }
#pragma unroll
  for (int h = 0; h < KV_; ++h) {
    float x = rowp[768 + h * 64 + l];
    float ss = x * x;
    for (int off = 32; off; off >>= 1) ss += __shfl_xor(ss, off);
    float xn = x * rsqrtf(ss * (1.f / 64.f) + EPS_) * kw[l];
    float o = xn;
    if (rot) {
      float p = __shfl_xor(xn, 1);
      o = (l & 1) ? (p * sn + xn * cs) : (xn * cs - p * sn);
    }
    Kb[((size_t)(b * KV_ + h) * S_ + s) * 64 + l] = f2bf(o);
    float v = rowp[1024 + h * 64 + l];
    Vt[((size_t)(b * KV_ + h) * 64 + l) * SKP + s] = f2bf(v);
  }
}

// ---------------- fused attention ----------------
// block = (b, h, QBLK=8 q-rows); 8 waves (512 thr); scores fp32 in dyn LDS [8][SCS]
// 34.9KB dyn + 4KB static -> 4 blocks/CU -> 32 waves/CU (HW max).
__global__ __launch_bounds__(512) void attn_kernel(const unsigned short* __restrict__ Qb,
    const unsigned short* __restrict__ Kb, const unsigned short* __restrict__ Vt,
    unsigned short* __restrict__ ctx, float* __restrict__ attn_out) {
  extern __shared__ float Sc[];
  __shared__ float partial[4][64][4];
  // bijective XCD swizzle: 12384 blocks = 8 * 1548
  int bid = blockIdx.x;
  int swz = (bid & 7) * 1548 + (bid >> 3);
  int qt = swz % NQT;
  int h = (swz / NQT) % H_;
  int b = swz / (NQT * H_);
  int kvh = h / NREP;
  int q0 = qt * QBLK;
  int tid = threadIdx.x;
  int l = tid & 63, w = tid >> 6;          // w in [0,8)
  int lr = l & 15, lk = (l >> 4) * 8;

  const unsigned short* Qbase = Qb + (size_t)(b * H_ + h) * S_ * 64;
  const unsigned short* Kbase = Kb + (size_t)(b * KV_ + kvh) * S_ * 64;
  const unsigned short* Vbase = Vt + (size_t)(b * KV_ + kvh) * 64 * SKP;

  // Q fragments (scale pre-folded); A-rows 8..15 are next-block rows, outputs discarded
  int qrow = q0 + lr; if (qrow >= S_) qrow = S_ - 1;
  bf16x8 qf0 = *(const bf16x8*)(Qbase + (size_t)qrow * 64 + lk);
  bf16x8 qf1 = *(const bf16x8*)(Qbase + (size_t)qrow * 64 + 32 + lk);

  // Phase 1: QK^T. sweep t covers keys t*128 + w*16; t=8 only waves 0-3 (keys 1024..1087).
  {
    const int kcol = w * 16 + lr;
    const int nT = (w < 4) ? 9 : 8;
    const unsigned short* kp = Kbase + (size_t)kcol * 64;   // t=0: kcol<128 valid
    bf16x8 kf0 = *(const bf16x8*)(kp + lk);
    bf16x8 kf1 = *(const bf16x8*)(kp + 32 + lk);
    for (int t = 0; t < nT; ++t) {
      bf16x8 nf0 = kf0, nf1 = kf1;
      if (t + 1 < nT) {
        int kr = (t + 1) * 128 + kcol; if (kr >= S_) kr = S_ - 1;
        const unsigned short* np = Kbase + (size_t)kr * 64;
        nf0 = *(const bf16x8*)(np + lk);
        nf1 = *(const bf16x8*)(np + 32 + lk);
      }
      f32x4 acc = {};
      acc = __builtin_amdgcn_mfma_f32_16x16x32_bf16(qf0, kf0, acc, 0, 0, 0);
      acc = __builtin_amdgcn_mfma_f32_16x16x32_bf16(qf1, kf1, acc, 0, 0, 0);
      if (l < 32) {                         // rows 0..7 real only
        int col = t * 128 + kcol;
        int rowb = (l >> 4) * 4;
#pragma unroll
        for (int r = 0; r < 4; ++r) Sc[(size_t)(rowb + r) * SCS + col] = acc[r];
      }
      kf0 = nf0; kf1 = nf1;
    }
  }
  __syncthreads();

  // Phase 2: softmax, one row per wave; coalesced nt dword stores; bf16 P writeback to LDS.
  {
    int q = q0 + w;
    float* srow = Sc + (size_t)w * SCS;
    float vals[17];
    float mx = -1e30f;
#pragma unroll
    for (int i = 0; i < 17; ++i) {
      int key = l + i * 64;
      float v = (key < S_) ? srow[key] : -1e30f;
      vals[i] = v;
      mx = fmaxf(mx, v);
    }
    for (int off = 32; off; off >>= 1) mx = fmaxf(mx, __shfl_xor(mx, off));
    float sum = 0.f;
#pragma unroll
    for (int i = 0; i < 17; ++i) {
      float e = __expf(vals[i] - mx);
      vals[i] = e; sum += e;
    }
    for (int off = 32; off; off >>= 1) sum += __shfl_xor(sum, off);
    float inv = 1.f / sum;
    if (q < S_) {
      float* gout = attn_out + ((size_t)(b * H_ + h) * S_ + q) * S_;
#pragma unroll
      for (int i = 0; i < 17; ++i) {
        int key = l + i * 64;
        if (key < S_) __builtin_nontemporal_store(vals[i] * inv, gout + key);
      }
    }
    unsigned short* urow = (unsigned short*)srow;
#pragma unroll
    for (int i = 0; i < 17; ++i) {
      int key = l + i * 64;
      float p = (key < S_) ? vals[i] * inv : 0.f;
      urow[key] = f2bf(p);                 // zero pads for PV
    }
  }
  __syncthreads();

  // Phase 3: PV. wave w: d-block (w&3)*16, key-half (w>>2)*544; 17 kc steps of 32.
  f32x4 accv = {};
  {
    const int d0 = (w & 3) * 16;
    const int kh = (w >> 2) * 544;
    const unsigned short* U = (const unsigned short*)Sc;
    const int prow = (lr & 7) * (SCS * 2);  // A-rows 8..15 duplicate 0..7, discarded
    const unsigned short* vb = Vbase + (size_t)(d0 + lr) * SKP + kh;
#pragma unroll 4
    for (int kc = 0; kc < 17; ++kc) {
      bf16x8 pa = *(const bf16x8*)&U[prow + kh + kc * 32 + lk];
      bf16x8 vf = *(const bf16x8*)(vb + kc * 32 + lk);
      accv = __builtin_amdgcn_mfma_f32_16x16x32_bf16(pa, vf, accv, 0, 0, 0);
    }
  }
  if (w >= 4) *(f32x4*)partial[w - 4][l] = accv;
  __syncthreads();
  if (w < 4 && l < 32) {
    accv += *(const f32x4*)partial[w][l];
    int rowb = (l >> 4) * 4;
    int d0 = (w & 3) * 16;
#pragma unroll
    for (int r = 0; r < 4; ++r) {
      int q = q0 + rowb + r;
      if (q < S_)
        ctx[(size_t)(b * S_ + q) * 768 + h * 64 + d0 + lr] = f2bf(accv[r]);
    }
  }
}

// ---------------- launch ----------------
extern "C" void kernel_launch(void* const* d_in, const int* in_sizes, int n_in,
                              void* d_out, int out_size, void* d_ws, size_t ws_size,
                              hipStream_t stream) {
  const float* hidden = (const float*)d_in[0];
  const int* pos_ids = (const int*)d_in[2];
  const int* ghp = (const int*)d_in[3];
  const int* gwp = (const int*)d_in[4];
  const float* Wq = (const float*)d_in[5];
  const float* Wk = (const float*)d_in[6];
  const float* Wv = (const float*)d_in[7];
  const float* Wo = (const float*)d_in[8];
  const float* qnw = (const float*)d_in[9];
  const float* knw = (const float*)d_in[10];

  char* ws = (char*)d_ws;
  unsigned short* Xb    = (unsigned short*)ws;                   // 12,595,200
  unsigned short* WqkvT = (unsigned short*)(ws + 12595200);      //  1,966,080
  unsigned short* WoT   = (unsigned short*)(ws + 14561280);      //  1,179,648
  float*          QKV   = (float*)(ws + 15740928);               // 41,984,000
  unsigned short* ctx   = (unsigned short*)(ws + 15740928);      // alias (after QKV consumed)
  unsigned short* Qb    = (unsigned short*)(ws + 57724928);      // 12,595,200
  unsigned short* Kb    = (unsigned short*)(ws + 70320128);      //  4,198,400
  unsigned short* Vt    = (unsigned short*)(ws + 74518528);      //  4,456,448

  float* out0 = (float*)d_out;
  float* attn_out = out0 + (size_t)B_ * S_ * D_;

  cast_x_kernel<<<6150, 256, 0, stream>>>(hidden, Xb, 1574400);
  cast_wqkv_kernel<<<3840, 256, 0, stream>>>(Wq, Wk, Wv, WqkvT);
  cast_wo_kernel<<<2304, 256, 0, stream>>>(Wo, WoT);

  gemm_bt<<<65 * 10, 256, 0, stream>>>(Xb, WqkvT, QKV, B_ * S_, 1280, D_);

  hipMemsetAsync(Vt, 0, 4456448, stream);
  qkv_epilogue<<<2050, 256, 0, stream>>>(QKV, pos_ids, ghp, gwp, qnw, knw, Qb, Kb, Vt);

  hipFuncSetAttribute((const void*)attn_kernel,
                      hipFuncAttributeMaxDynamicSharedMemorySize, QBLK * SCS * 4);
  attn_kernel<<<B_ * H_ * NQT, 512, QBLK * SCS * 4, stream>>>(Qb, Kb, Vt, ctx, attn_out);

  gemm_bt<<<65 * 6, 256, 0, stream>>>(ctx, WoT, out0, B_ * S_, D_, D_);
}

// Round 5
// 354.776 us; speedup vs baseline: 1.4561x; 1.4561x over previous
//
#include <hip/hip_runtime.h>

#define B_ 8
#define S_ 1025
#define D_ 768
#define H_ 12
#define KV_ 4
#define HD_ 64
#define NREP 3
#define SCALE_ 0.125f
#define EPS_ 1e-6f
#define SKP 1088   // padded key count (17*64)
#define SCS 1092   // LDS score row stride in floats (4368 B)
#define PST 1096   // packed bf16 P row stride in ushorts (2192 B = 16 mod 128 -> slot-rotating)
#define QBLK 16    // q-rows per block
#define NQT 65     // ceil(1025/16)

typedef __attribute__((ext_vector_type(8))) short bf16x8;
typedef __attribute__((ext_vector_type(4))) float f32x4;

__device__ __forceinline__ unsigned short f2bf(float f) {
  unsigned int u = __builtin_bit_cast(unsigned int, f);
  return (unsigned short)((u + 0x7FFFu + ((u >> 16) & 1u)) >> 16);
}
__device__ __forceinline__ unsigned int pk2(float a, float b) {
  return (unsigned int)f2bf(a) | ((unsigned int)f2bf(b) << 16);
}

// ---------------- casts ----------------
__global__ __launch_bounds__(256) void cast_x_kernel(const float* __restrict__ x,
                                                     unsigned short* __restrict__ xb, int n4) {
  int i = blockIdx.x * 256 + threadIdx.x;
  if (i >= n4) return;
  f32x4 v = *(const f32x4*)(x + (size_t)i * 4);
  uint2 o;
  o.x = pk2(v[0], v[1]);
  o.y = pk2(v[2], v[3]);
  *(uint2*)(xb + (size_t)i * 4) = o;
}

__global__ __launch_bounds__(256) void cast_wqkv_kernel(const float* __restrict__ Wq,
    const float* __restrict__ Wk, const float* __restrict__ Wv,
    unsigned short* __restrict__ WT) {
  int idx = blockIdx.x * 256 + threadIdx.x;  // = n*768 + k
  int n = idx / D_, k = idx % D_;
  float v;
  if (n < 768)       v = Wq[(size_t)k * 768 + n];
  else if (n < 1024) v = Wk[(size_t)k * 256 + (n - 768)];
  else               v = Wv[(size_t)k * 256 + (n - 1024)];
  WT[idx] = f2bf(v);
}

__global__ __launch_bounds__(256) void cast_wo_kernel(const float* __restrict__ Wo,
                                                      unsigned short* __restrict__ WT) {
  int idx = blockIdx.x * 256 + threadIdx.x;  // = n*768 + k
  int n = idx / D_, k = idx % D_;
  WT[idx] = f2bf(Wo[(size_t)k * D_ + n]);
}

// ---------------- GEMM: C[M][N] fp32 = A[M][K] bf16 @ BT[N][K] bf16 ----------------
#define BM 128
#define BN 128
#define BK 32
#define LSTR 40   // padded LDS row stride (ushorts)
__global__ __launch_bounds__(256) void gemm_bt(const unsigned short* __restrict__ A,
    const unsigned short* __restrict__ BT, float* __restrict__ C, int M, int N, int K) {
  __shared__ unsigned short As[BM * LSTR];
  __shared__ unsigned short Bs[BN * LSTR];
  const int nMt = (M + BM - 1) / BM;
  const int tm = blockIdx.x % nMt;
  const int tn = blockIdx.x / nMt;
  const int row0 = tm * BM, col0 = tn * BN;
  const int tid = threadIdx.x;
  const int l = tid & 63, w = tid >> 6;
  const int wr = (w >> 1) * 64, wc = (w & 1) * 64;
  const int lr = l & 15, lk = (l >> 4) * 8;
  f32x4 acc[4][4] = {};
  for (int kt = 0; kt < K; kt += BK) {
    __syncthreads();
#pragma unroll
    for (int i = 0; i < 2; ++i) {
      int c = tid + i * 256;
      int r = c >> 2;
      int ce = (c & 3) * 8;
      int gr = row0 + r; gr = gr < M ? gr : M - 1;
      bf16x8 va = *(const bf16x8*)(A + (size_t)gr * K + kt + ce);
      *(bf16x8*)&As[r * LSTR + ce] = va;
      bf16x8 vb = *(const bf16x8*)(BT + (size_t)(col0 + r) * K + kt + ce);
      *(bf16x8*)&Bs[r * LSTR + ce] = vb;
    }
    __syncthreads();
    bf16x8 af[4], bfr[4];
#pragma unroll
    for (int m = 0; m < 4; ++m)
      af[m] = *(const bf16x8*)&As[(wr + m * 16 + lr) * LSTR + lk];
#pragma unroll
    for (int n = 0; n < 4; ++n)
      bfr[n] = *(const bf16x8*)&Bs[(wc + n * 16 + lr) * LSTR + lk];
#pragma unroll
    for (int m = 0; m < 4; ++m)
#pragma unroll
      for (int n = 0; n < 4; ++n)
        acc[m][n] = __builtin_amdgcn_mfma_f32_16x16x32_bf16(af[m], bfr[n], acc[m][n], 0, 0, 0);
  }
  const int orow = (l >> 4) * 4;
#pragma unroll
  for (int m = 0; m < 4; ++m)
#pragma unroll
    for (int n = 0; n < 4; ++n)
#pragma unroll
      for (int r = 0; r < 4; ++r) {
        int row = row0 + wr + m * 16 + orow + r;
        int col = col0 + wc + n * 16 + lr;
        if (row < M) C[(size_t)row * N + col] = acc[m][n][r];
      }
}

// ---------------- QKV epilogue: rmsnorm + rope + layouts ----------------
__global__ __launch_bounds__(256) void qkv_epilogue(const float* __restrict__ QKV,
    const int* __restrict__ pos_ids, const int* __restrict__ ghp, const int* __restrict__ gwp,
    const float* __restrict__ qw, const float* __restrict__ kw,
    unsigned short* __restrict__ Qb, unsigned short* __restrict__ Kb,
    unsigned short* __restrict__ Vt) {
  int tok = blockIdx.x * 4 + (threadIdx.x >> 6);
  int l = threadIdx.x & 63;
  if (tok >= B_ * S_) return;
  int b = tok / S_, s = tok % S_;
  const float* rowp = QKV + (size_t)tok * 1280;
  bool rot = (s > 0);
  float cs = 1.f, sn = 0.f;
  if (rot) {
    int gh = ghp[0], gw = gwp[0];
    int pos = pos_ids[tok];
    int hi = (pos / gw) % gh;
    int wi = pos % gw;
    int pi = l >> 1;
    int j = pi < 16 ? pi : pi - 16;
    float invf = exp2f(-(float)j * (13.287712379549449f / 16.f)); // 10000^(-j/16)
    float ang = (pi < 16 ? (float)hi : (float)wi) * invf;
    cs = cosf(ang); sn = sinf(ang);
  }
#pragma unroll
  for (int h = 0; h < H_; ++h) {
    float x = rowp[h * 64 + l];
    float ss = x * x;
    for (int off = 32; off; off >>= 1) ss += __shfl_xor(ss, off);
    float xn = x * rsqrtf(ss * (1.f / 64.f) + EPS_) * qw[l];
    float o = xn;
    if (rot) {
      float p = __shfl_xor(xn, 1);
      o = (l & 1) ? (p * sn + xn * cs) : (xn * cs - p * sn);
    }
    o *= SCALE_;
    Qb[((size_t)(b * H_ + h) * S_ + s) * 64 + l] = f2bf(o);
  }
#pragma unroll
  for (int h = 0; h < KV_; ++h) {
    float x = rowp[768 + h * 64 + l];
    float ss = x * x;
    for (int off = 32; off; off >>= 1) ss += __shfl_xor(ss, off);
    float xn = x * rsqrtf(ss * (1.f / 64.f) + EPS_) * kw[l];
    float o = xn;
    if (rot) {
      float p = __shfl_xor(xn, 1);
      o = (l & 1) ? (p * sn + xn * cs) : (xn * cs - p * sn);
    }
    Kb[((size_t)(b * KV_ + h) * S_ + s) * 64 + l] = f2bf(o);
    float v = rowp[1024 + h * 64 + l];
    Vt[((size_t)(b * KV_ + h) * 64 + l) * SKP + s] = f2bf(v);
  }
}

// ---------------- fused attention ----------------
// block = (b, h, 16 q-rows); 8 waves (512 thr); 2 blocks/CU.
// Key idea: NO global stores before any __syncthreads (each __syncthreads drains
// vmcnt(0)); all attn stores issue at the very end from register-held softmax values.
__global__ __launch_bounds__(512, 4) void attn_kernel(const unsigned short* __restrict__ Qb,
    const unsigned short* __restrict__ Kb, const unsigned short* __restrict__ Vt,
    unsigned short* __restrict__ ctx, float* __restrict__ attn_out) {
  extern __shared__ float Sc[];
  __shared__ float partial[4][64][4];
  // bijective XCD swizzle: 6240 blocks = 8 * 780
  int bid = blockIdx.x;
  int swz = (bid & 7) * 780 + (bid >> 3);
  int qt = swz % NQT;
  int h = (swz / NQT) % H_;
  int b = swz / (NQT * H_);
  int kvh = h / NREP;
  int q0 = qt * QBLK;
  int tid = threadIdx.x;
  int l = tid & 63, w = tid >> 6;          // w in [0,8)
  int lr = l & 15, lk = (l >> 4) * 8;

  const unsigned short* Qbase = Qb + (size_t)(b * H_ + h) * S_ * 64;
  const unsigned short* Kbase = Kb + (size_t)(b * KV_ + kvh) * S_ * 64;
  const unsigned short* Vbase = Vt + (size_t)(b * KV_ + kvh) * 64 * SKP;

  // Q fragments (scale pre-folded)
  int qrow = q0 + lr; if (qrow >= S_) qrow = S_ - 1;
  bf16x8 qf0 = *(const bf16x8*)(Qbase + (size_t)qrow * 64 + lk);
  bf16x8 qf1 = *(const bf16x8*)(Qbase + (size_t)qrow * 64 + 32 + lk);

  // Phase 1: QK^T. sweep t covers keys t*128 + w*16; t=8 only waves 0-3 (keys 1024..1087).
  {
    const int kcol = w * 16 + lr;
    const int nT = (w < 4) ? 9 : 8;
    const unsigned short* kp = Kbase + (size_t)kcol * 64;   // t=0: kcol<128 valid
    bf16x8 kf0 = *(const bf16x8*)(kp + lk);
    bf16x8 kf1 = *(const bf16x8*)(kp + 32 + lk);
    for (int t = 0; t < nT; ++t) {
      bf16x8 nf0 = kf0, nf1 = kf1;
      if (t + 1 < nT) {
        int kr = (t + 1) * 128 + kcol; if (kr >= S_) kr = S_ - 1;
        const unsigned short* np = Kbase + (size_t)kr * 64;
        nf0 = *(const bf16x8*)(np + lk);
        nf1 = *(const bf16x8*)(np + 32 + lk);
      }
      f32x4 acc = {};
      acc = __builtin_amdgcn_mfma_f32_16x16x32_bf16(qf0, kf0, acc, 0, 0, 0);
      acc = __builtin_amdgcn_mfma_f32_16x16x32_bf16(qf1, kf1, acc, 0, 0, 0);
      int col = t * 128 + kcol;            // <= 1087 by construction
      int rowb = (l >> 4) * 4;
#pragma unroll
      for (int r = 0; r < 4; ++r) Sc[(size_t)(rowb + r) * SCS + col] = acc[r];
      kf0 = nf0; kf1 = nf1;
    }
  }
  __syncthreads();                         // B1 (no vmem stores outstanding)

  // Phase 2a: softmax rows {w, w+8}; normalized fp32 kept in registers.
  float vals[2][17];
#pragma unroll
  for (int rr = 0; rr < 2; ++rr) {
    int rowi = w + rr * 8;
    const float* srow = Sc + (size_t)rowi * SCS;
    float mx = -1e30f;
#pragma unroll
    for (int i = 0; i < 17; ++i) {
      int key = l + i * 64;
      float v = (key < S_) ? srow[key] : -1e30f;
      vals[rr][i] = v;
      mx = fmaxf(mx, v);
    }
    for (int off = 32; off; off >>= 1) mx = fmaxf(mx, __shfl_xor(mx, off));
    float sum = 0.f;
#pragma unroll
    for (int i = 0; i < 17; ++i) {
      float e = __expf(vals[rr][i] - mx);
      vals[rr][i] = e; sum += e;
    }
    for (int off = 32; off; off >>= 1) sum += __shfl_xor(sum, off);
    float inv = 1.f / sum;
#pragma unroll
    for (int i = 0; i < 17; ++i) {
      int key = l + i * 64;
      vals[rr][i] = (key < S_) ? vals[rr][i] * inv : 0.f;
    }
  }
  __syncthreads();                         // B2a: all fp32 score reads done

  // Phase 2b: write packed bf16 P, row stride PST (slot-rotating -> conflict-free b128 reads)
  {
    unsigned short* P = (unsigned short*)Sc;
#pragma unroll
    for (int rr = 0; rr < 2; ++rr) {
      int rowi = w + rr * 8;
      unsigned short* prow = P + (size_t)rowi * PST;
#pragma unroll
      for (int i = 0; i < 17; ++i) prow[l + i * 64] = f2bf(vals[rr][i]);
    }
  }
  __syncthreads();                         // B2b

  // Phase 3: PV. wave w: d-block (w&3)*16, key-half (w>>2)*544; 17 kc steps of 32.
  f32x4 accv = {};
  {
    const int d0 = (w & 3) * 16;
    const int kh = (w >> 2) * 544;
    const unsigned short* U = (const unsigned short*)Sc;
    const int prow = lr * PST;
    const unsigned short* vb = Vbase + (size_t)(d0 + lr) * SKP + kh;
#pragma unroll 4
    for (int kc = 0; kc < 17; ++kc) {
      bf16x8 pa = *(const bf16x8*)&U[prow + kh + kc * 32 + lk];
      bf16x8 vf = *(const bf16x8*)(vb + kc * 32 + lk);
      accv = __builtin_amdgcn_mfma_f32_16x16x32_bf16(pa, vf, accv, 0, 0, 0);
    }
  }
  if (w >= 4) *(f32x4*)partial[w - 4][l] = accv;
  __syncthreads();                         // B3 (V loads consumed; still no stores)
  if (w < 4) {
    accv += *(const f32x4*)partial[w][l];
    int rowb = (l >> 4) * 4;
    int d0 = (w & 3) * 16;
#pragma unroll
    for (int r = 0; r < 4; ++r) {
      int q = q0 + rowb + r;
      if (q < S_)
        ctx[(size_t)(b * S_ + q) * 768 + h * 64 + d0 + lr] = f2bf(accv[r]);
    }
  }

  // Phase 4: attn global stores (nontemporal), nothing ever waits on these.
#pragma unroll
  for (int rr = 0; rr < 2; ++rr) {
    int q = q0 + w + rr * 8;
    if (q < S_) {
      float* gout = attn_out + ((size_t)(b * H_ + h) * S_ + q) * S_;
#pragma unroll
      for (int i = 0; i < 16; ++i)
        __builtin_nontemporal_store(vals[rr][i], gout + l + i * 64);
      if (l == 0) __builtin_nontemporal_store(vals[rr][16], gout + 1024);
    }
  }
}

// ---------------- launch ----------------
extern "C" void kernel_launch(void* const* d_in, const int* in_sizes, int n_in,
                              void* d_out, int out_size, void* d_ws, size_t ws_size,
                              hipStream_t stream) {
  const float* hidden = (const float*)d_in[0];
  const int* pos_ids = (const int*)d_in[2];
  const int* ghp = (const int*)d_in[3];
  const int* gwp = (const int*)d_in[4];
  const float* Wq = (const float*)d_in[5];
  const float* Wk = (const float*)d_in[6];
  const float* Wv = (const float*)d_in[7];
  const float* Wo = (const float*)d_in[8];
  const float* qnw = (const float*)d_in[9];
  const float* knw = (const float*)d_in[10];

  char* ws = (char*)d_ws;
  unsigned short* Xb    = (unsigned short*)ws;                   // 12,595,200
  unsigned short* WqkvT = (unsigned short*)(ws + 12595200);      //  1,966,080
  unsigned short* WoT   = (unsigned short*)(ws + 14561280);      //  1,179,648
  float*          QKV   = (float*)(ws + 15740928);               // 41,984,000
  unsigned short* ctx   = (unsigned short*)(ws + 15740928);      // alias (after QKV consumed)
  unsigned short* Qb    = (unsigned short*)(ws + 57724928);      // 12,595,200
  unsigned short* Kb    = (unsigned short*)(ws + 70320128);      //  4,198,400
  unsigned short* Vt    = (unsigned short*)(ws + 74518528);      //  4,456,448

  float* out0 = (float*)d_out;
  float* attn_out = out0 + (size_t)B_ * S_ * D_;

  cast_x_kernel<<<6150, 256, 0, stream>>>(hidden, Xb, 1574400);
  cast_wqkv_kernel<<<3840, 256, 0, stream>>>(Wq, Wk, Wv, WqkvT);
  cast_wo_kernel<<<2304, 256, 0, stream>>>(Wo, WoT);

  gemm_bt<<<65 * 10, 256, 0, stream>>>(Xb, WqkvT, QKV, B_ * S_, 1280, D_);

  hipMemsetAsync(Vt, 0, 4456448, stream);
  qkv_epilogue<<<2050, 256, 0, stream>>>(QKV, pos_ids, ghp, gwp, qnw, knw, Qb, Kb, Vt);

  hipFuncSetAttribute((const void*)attn_kernel,
                      hipFuncAttributeMaxDynamicSharedMemorySize, QBLK * SCS * 4);
  attn_kernel<<<B_ * H_ * NQT, 512, QBLK * SCS * 4, stream>>>(Qb, Kb, Vt, ctx, attn_out);

  gemm_bt<<<65 * 6, 256, 0, stream>>>(ctx, WoT, out0, B_ * S_, D_, D_);
}

// Round 6
// 340.034 us; speedup vs baseline: 1.5192x; 1.0434x over previous
//
#include <hip/hip_runtime.h>
#include <hip/hip_fp16.h>

#define B_ 8
#define S_ 1025
#define D_ 768
#define H_ 12
#define KV_ 4
#define HD_ 64
#define NREP 3
#define SCALE_ 0.125f
#define EPS_ 1e-6f
#define SKP 1088   // padded key count (17*64)
#define HSS 1092   // LDS half-score row stride in halfs (2184 B)
#define PST 1096   // packed bf16 P row stride in ushorts (2192 B = 16 mod 128 -> slot-rotating)
#define QBLK 16    // q-rows per block
#define NQT 65     // ceil(1025/16)
#define DYNLDS 35072  // max(16*2184, 16*2192) bytes

typedef __attribute__((ext_vector_type(8))) short bf16x8;
typedef __attribute__((ext_vector_type(4))) float f32x4;
typedef __attribute__((ext_vector_type(2))) float f32x2;

__device__ __forceinline__ unsigned short f2bf(float f) {
  unsigned int u = __builtin_bit_cast(unsigned int, f);
  return (unsigned short)((u + 0x7FFFu + ((u >> 16) & 1u)) >> 16);
}
__device__ __forceinline__ unsigned int pk2(float a, float b) {
  return (unsigned int)f2bf(a) | ((unsigned int)f2bf(b) << 16);
}
__device__ __forceinline__ float bf2f(unsigned int u) {
  return __builtin_bit_cast(float, u << 16);
}

// ---------------- casts ----------------
__global__ __launch_bounds__(256) void cast_x_kernel(const float* __restrict__ x,
                                                     unsigned short* __restrict__ xb, int n4) {
  int i = blockIdx.x * 256 + threadIdx.x;
  if (i >= n4) return;
  f32x4 v = *(const f32x4*)(x + (size_t)i * 4);
  uint2 o;
  o.x = pk2(v[0], v[1]);
  o.y = pk2(v[2], v[3]);
  *(uint2*)(xb + (size_t)i * 4) = o;
}

__global__ __launch_bounds__(256) void cast_wqkv_kernel(const float* __restrict__ Wq,
    const float* __restrict__ Wk, const float* __restrict__ Wv,
    unsigned short* __restrict__ WT) {
  int idx = blockIdx.x * 256 + threadIdx.x;  // = n*768 + k
  int n = idx / D_, k = idx % D_;
  float v;
  if (n < 768)       v = Wq[(size_t)k * 768 + n];
  else if (n < 1024) v = Wk[(size_t)k * 256 + (n - 768)];
  else               v = Wv[(size_t)k * 256 + (n - 1024)];
  WT[idx] = f2bf(v);
}

__global__ __launch_bounds__(256) void cast_wo_kernel(const float* __restrict__ Wo,
                                                      unsigned short* __restrict__ WT) {
  int idx = blockIdx.x * 256 + threadIdx.x;  // = n*768 + k
  int n = idx / D_, k = idx % D_;
  WT[idx] = f2bf(Wo[(size_t)k * D_ + n]);
}

// ---------------- GEMM: C[M][N] fp32 = A[M][K] bf16 @ BT[N][K] bf16 ----------------
#define BM 128
#define BN 128
#define BK 32
#define LSTR 40   // padded LDS row stride (ushorts)
__global__ __launch_bounds__(256) void gemm_bt(const unsigned short* __restrict__ A,
    const unsigned short* __restrict__ BT, float* __restrict__ C, int M, int N, int K) {
  __shared__ unsigned short As[BM * LSTR];
  __shared__ unsigned short Bs[BN * LSTR];
  const int nMt = (M + BM - 1) / BM;
  const int tm = blockIdx.x % nMt;
  const int tn = blockIdx.x / nMt;
  const int row0 = tm * BM, col0 = tn * BN;
  const int tid = threadIdx.x;
  const int l = tid & 63, w = tid >> 6;
  const int wr = (w >> 1) * 64, wc = (w & 1) * 64;
  const int lr = l & 15, lk = (l >> 4) * 8;
  f32x4 acc[4][4] = {};
  for (int kt = 0; kt < K; kt += BK) {
    __syncthreads();
#pragma unroll
    for (int i = 0; i < 2; ++i) {
      int c = tid + i * 256;
      int r = c >> 2;
      int ce = (c & 3) * 8;
      int gr = row0 + r; gr = gr < M ? gr : M - 1;
      bf16x8 va = *(const bf16x8*)(A + (size_t)gr * K + kt + ce);
      *(bf16x8*)&As[r * LSTR + ce] = va;
      bf16x8 vb = *(const bf16x8*)(BT + (size_t)(col0 + r) * K + kt + ce);
      *(bf16x8*)&Bs[r * LSTR + ce] = vb;
    }
    __syncthreads();
    bf16x8 af[4], bfr[4];
#pragma unroll
    for (int m = 0; m < 4; ++m)
      af[m] = *(const bf16x8*)&As[(wr + m * 16 + lr) * LSTR + lk];
#pragma unroll
    for (int n = 0; n < 4; ++n)
      bfr[n] = *(const bf16x8*)&Bs[(wc + n * 16 + lr) * LSTR + lk];
#pragma unroll
    for (int m = 0; m < 4; ++m)
#pragma unroll
      for (int n = 0; n < 4; ++n)
        acc[m][n] = __builtin_amdgcn_mfma_f32_16x16x32_bf16(af[m], bfr[n], acc[m][n], 0, 0, 0);
  }
  const int orow = (l >> 4) * 4;
#pragma unroll
  for (int m = 0; m < 4; ++m)
#pragma unroll
    for (int n = 0; n < 4; ++n)
#pragma unroll
      for (int r = 0; r < 4; ++r) {
        int row = row0 + wr + m * 16 + orow + r;
        int col = col0 + wc + n * 16 + lr;
        if (row < M) C[(size_t)row * N + col] = acc[m][n][r];
      }
}

// ---------------- QKV epilogue: rmsnorm + rope + layouts ----------------
__global__ __launch_bounds__(256) void qkv_epilogue(const float* __restrict__ QKV,
    const int* __restrict__ pos_ids, const int* __restrict__ ghp, const int* __restrict__ gwp,
    const float* __restrict__ qw, const float* __restrict__ kw,
    unsigned short* __restrict__ Qb, unsigned short* __restrict__ Kb,
    unsigned short* __restrict__ Vt) {
  int tok = blockIdx.x * 4 + (threadIdx.x >> 6);
  int l = threadIdx.x & 63;
  if (tok >= B_ * S_) return;
  int b = tok / S_, s = tok % S_;
  const float* rowp = QKV + (size_t)tok * 1280;
  bool rot = (s > 0);
  float cs = 1.f, sn = 0.f;
  if (rot) {
    int gh = ghp[0], gw = gwp[0];
    int pos = pos_ids[tok];
    int hi = (pos / gw) % gh;
    int wi = pos % gw;
    int pi = l >> 1;
    int j = pi < 16 ? pi : pi - 16;
    float invf = exp2f(-(float)j * (13.287712379549449f / 16.f)); // 10000^(-j/16)
    float ang = (pi < 16 ? (float)hi : (float)wi) * invf;
    cs = cosf(ang); sn = sinf(ang);
  }
#pragma unroll
  for (int h = 0; h < H_; ++h) {
    float x = rowp[h * 64 + l];
    float ss = x * x;
    for (int off = 32; off; off >>= 1) ss += __shfl_xor(ss, off);
    float xn = x * rsqrtf(ss * (1.f / 64.f) + EPS_) * qw[l];
    float o = xn;
    if (rot) {
      float p = __shfl_xor(xn, 1);
      o = (l & 1) ? (p * sn + xn * cs) : (xn * cs - p * sn);
    }
    o *= SCALE_;
    Qb[((size_t)(b * H_ + h) * S_ + s) * 64 + l] = f2bf(o);
  }
#pragma unroll
  for (int h = 0; h < KV_; ++h) {
    float x = rowp[768 + h * 64 + l];
    float ss = x * x;
    for (int off = 32; off; off >>= 1) ss += __shfl_xor(ss, off);
    float xn = x * rsqrtf(ss * (1.f / 64.f) + EPS_) * kw[l];
    float o = xn;
    if (rot) {
      float p = __shfl_xor(xn, 1);
      o = (l & 1) ? (p * sn + xn * cs) : (xn * cs - p * sn);
    }
    Kb[((size_t)(b * KV_ + h) * S_ + s) * 64 + l] = f2bf(o);
    float v = rowp[1024 + h * 64 + l];
    Vt[((size_t)(b * KV_ + h) * 64 + l) * SKP + s] = f2bf(v);
  }
}

// ---------------- fused attention ----------------
// block = (b, h, 16 q-rows); 8 waves (512 thr); fp16 scores -> 35KB dyn LDS
// -> 4 blocks/CU = 32 waves/CU. All global stores at kernel end.
__global__ __launch_bounds__(512, 8) void attn_kernel(const unsigned short* __restrict__ Qb,
    const unsigned short* __restrict__ Kb, const unsigned short* __restrict__ Vt,
    unsigned short* __restrict__ ctx, float* __restrict__ attn_out) {
  extern __shared__ unsigned short Ush[];   // aliased: fp16 scores [16][HSS] / bf16 P [16][PST]
  __shared__ float partial[4][64][4];
  __shared__ float invsh[16];
  // bijective XCD swizzle: 6240 blocks = 8 * 780
  int bid = blockIdx.x;
  int swz = (bid & 7) * 780 + (bid >> 3);
  int qt = swz % NQT;
  int h = (swz / NQT) % H_;
  int b = swz / (NQT * H_);
  int kvh = h / NREP;
  int q0 = qt * QBLK;
  int tid = threadIdx.x;
  int l = tid & 63, w = tid >> 6;          // w in [0,8)
  int lr = l & 15, lk = (l >> 4) * 8;

  const unsigned short* Qbase = Qb + (size_t)(b * H_ + h) * S_ * 64;
  const unsigned short* Kbase = Kb + (size_t)(b * KV_ + kvh) * S_ * 64;
  const unsigned short* Vbase = Vt + (size_t)(b * KV_ + kvh) * 64 * SKP;

  // Q fragments (scale pre-folded)
  int qrow = q0 + lr; if (qrow >= S_) qrow = S_ - 1;
  bf16x8 qf0 = *(const bf16x8*)(Qbase + (size_t)qrow * 64 + lk);
  bf16x8 qf1 = *(const bf16x8*)(Qbase + (size_t)qrow * 64 + 32 + lk);

  // Phase 1: QK^T -> fp16 scores in LDS. keys t*128 + w*16; t=8 only waves 0-3.
  {
    const int kcol = w * 16 + lr;
    const int nT = (w < 4) ? 9 : 8;
    const unsigned short* kp = Kbase + (size_t)kcol * 64;   // t=0: kcol<128 valid
    bf16x8 kf0 = *(const bf16x8*)(kp + lk);
    bf16x8 kf1 = *(const bf16x8*)(kp + 32 + lk);
    for (int t = 0; t < nT; ++t) {
      bf16x8 nf0 = kf0, nf1 = kf1;
      if (t + 1 < nT) {
        int kr = (t + 1) * 128 + kcol; if (kr >= S_) kr = S_ - 1;
        const unsigned short* np = Kbase + (size_t)kr * 64;
        nf0 = *(const bf16x8*)(np + lk);
        nf1 = *(const bf16x8*)(np + 32 + lk);
      }
      f32x4 acc = {};
      acc = __builtin_amdgcn_mfma_f32_16x16x32_bf16(qf0, kf0, acc, 0, 0, 0);
      acc = __builtin_amdgcn_mfma_f32_16x16x32_bf16(qf1, kf1, acc, 0, 0, 0);
      int col = t * 128 + kcol;            // <= 1087
      int rowb = (l >> 4) * 4;
#pragma unroll
      for (int r = 0; r < 4; ++r)
        Ush[(size_t)(rowb + r) * HSS + col] =
            __builtin_bit_cast(unsigned short, __float2half(acc[r]));
      kf0 = nf0; kf1 = nf1;
    }
  }
  __syncthreads();                         // B1

  // Phase 2a: softmax rows {w, w+8}; lane owns key pairs {2l,2l+1}+128i.
  float invr[2];
  float ta[2], tasum;                      // per-row exp values kept only transiently
  f32x2 ef[2][8];
#pragma unroll
  for (int rr = 0; rr < 2; ++rr) {
    int rowi = w + rr * 8;
    const unsigned short* Hrow = Ush + (size_t)rowi * HSS;
    f32x2 f[8];
#pragma unroll
    for (int i = 0; i < 8; ++i) {
      __half2 hv = *(const __half2*)&Hrow[i * 128 + 2 * l];
      float2 fv = __half22float2(hv);
      f[i][0] = fv.x; f[i][1] = fv.y;
    }
    float tail = __half2float(*(const __half*)&Hrow[1024]);
    if (l != 0) tail = -1e30f;
    float mx = tail;
#pragma unroll
    for (int i = 0; i < 8; ++i) mx = fmaxf(mx, fmaxf(f[i][0], f[i][1]));
    for (int off = 32; off; off >>= 1) mx = fmaxf(mx, __shfl_xor(mx, off));
    float sum = 0.f;
#pragma unroll
    for (int i = 0; i < 8; ++i) {
      f[i][0] = __expf(f[i][0] - mx); f[i][1] = __expf(f[i][1] - mx);
      sum += f[i][0] + f[i][1];
      ef[rr][i] = f[i];
    }
    float te = __expf(tail - mx);          // 0 for l!=0
    ta[rr] = te;
    sum += te;
    for (int off = 32; off; off >>= 1) sum += __shfl_xor(sum, off);
    invr[rr] = 1.f / sum;
  }
  tasum = ta[0];  (void)tasum;
  __syncthreads();                         // B2a: all fp16 score reads done

  // Phase 2b: write unnormalized bf16 P at stride PST; store inv per row.
#pragma unroll
  for (int rr = 0; rr < 2; ++rr) {
    int rowi = w + rr * 8;
    unsigned short* Prow = Ush + (size_t)rowi * PST;
#pragma unroll
    for (int i = 0; i < 8; ++i)
      *(unsigned int*)&Prow[i * 128 + 2 * l] = pk2(ef[rr][i][0], ef[rr][i][1]);
    if (l < 32)
      *(unsigned int*)&Prow[1024 + 2 * l] = (l == 0) ? pk2(ta[rr], 0.f) : 0u;
    if (l == 0) invsh[rowi] = invr[rr];
  }
  __syncthreads();                         // B2b

  // Phase 3: PV (P unnormalized). wave w: d-block (w&3)*16, key-half (w>>2)*544.
  f32x4 accv = {};
  {
    const int d0 = (w & 3) * 16;
    const int kh = (w >> 2) * 544;
    const int prow = lr * PST;
    const unsigned short* vb = Vbase + (size_t)(d0 + lr) * SKP + kh;
#pragma unroll 4
    for (int kc = 0; kc < 17; ++kc) {
      bf16x8 pa = *(const bf16x8*)&Ush[prow + kh + kc * 32 + lk];
      bf16x8 vf = *(const bf16x8*)(vb + kc * 32 + lk);
      accv = __builtin_amdgcn_mfma_f32_16x16x32_bf16(pa, vf, accv, 0, 0, 0);
    }
  }
  if (w >= 4) *(f32x4*)partial[w - 4][l] = accv;
  __syncthreads();                         // B3
  if (w < 4) {
    accv += *(const f32x4*)partial[w][l];
    int rowb = (l >> 4) * 4;
    int d0 = (w & 3) * 16;
#pragma unroll
    for (int r = 0; r < 4; ++r) {
      int q = q0 + rowb + r;
      if (q < S_)
        ctx[(size_t)(b * S_ + q) * 768 + h * 64 + d0 + lr] = f2bf(accv[r] * invsh[rowb + r]);
    }
  }

  // Phase 4: attn global stores (nontemporal) from LDS P * inv; nothing waits on these.
#pragma unroll
  for (int rr = 0; rr < 2; ++rr) {
    int rowi = w + rr * 8;
    int q = q0 + rowi;
    if (q < S_) {
      float inv = invr[rr];
      const unsigned short* Prow = Ush + (size_t)rowi * PST;
      float* gout = attn_out + ((size_t)(b * H_ + h) * S_ + q) * S_;
#pragma unroll
      for (int i = 0; i < 8; ++i) {
        unsigned int d = *(const unsigned int*)&Prow[i * 128 + 2 * l];
        f32x2 o;
        o[0] = bf2f(d & 0xffffu) * inv;
        o[1] = bf2f(d >> 16) * inv;
        __builtin_nontemporal_store(o, (f32x2*)(gout + i * 128 + 2 * l));
      }
      if (l == 0) {
        unsigned int d = *(const unsigned int*)&Prow[1024];
        __builtin_nontemporal_store(bf2f(d & 0xffffu) * inv, gout + 1024);
      }
    }
  }
}

// ---------------- launch ----------------
extern "C" void kernel_launch(void* const* d_in, const int* in_sizes, int n_in,
                              void* d_out, int out_size, void* d_ws, size_t ws_size,
                              hipStream_t stream) {
  const float* hidden = (const float*)d_in[0];
  const int* pos_ids = (const int*)d_in[2];
  const int* ghp = (const int*)d_in[3];
  const int* gwp = (const int*)d_in[4];
  const float* Wq = (const float*)d_in[5];
  const float* Wk = (const float*)d_in[6];
  const float* Wv = (const float*)d_in[7];
  const float* Wo = (const float*)d_in[8];
  const float* qnw = (const float*)d_in[9];
  const float* knw = (const float*)d_in[10];

  char* ws = (char*)d_ws;
  unsigned short* Xb    = (unsigned short*)ws;                   // 12,595,200
  unsigned short* WqkvT = (unsigned short*)(ws + 12595200);      //  1,966,080
  unsigned short* WoT   = (unsigned short*)(ws + 14561280);      //  1,179,648
  float*          QKV   = (float*)(ws + 15740928);               // 41,984,000
  unsigned short* ctx   = (unsigned short*)(ws + 15740928);      // alias (after QKV consumed)
  unsigned short* Qb    = (unsigned short*)(ws + 57724928);      // 12,595,200
  unsigned short* Kb    = (unsigned short*)(ws + 70320128);      //  4,198,400
  unsigned short* Vt    = (unsigned short*)(ws + 74518528);      //  4,456,448

  float* out0 = (float*)d_out;
  float* attn_out = out0 + (size_t)B_ * S_ * D_;

  cast_x_kernel<<<6150, 256, 0, stream>>>(hidden, Xb, 1574400);
  cast_wqkv_kernel<<<3840, 256, 0, stream>>>(Wq, Wk, Wv, WqkvT);
  cast_wo_kernel<<<2304, 256, 0, stream>>>(Wo, WoT);

  gemm_bt<<<65 * 10, 256, 0, stream>>>(Xb, WqkvT, QKV, B_ * S_, 1280, D_);

  hipMemsetAsync(Vt, 0, 4456448, stream);
  qkv_epilogue<<<2050, 256, 0, stream>>>(QKV, pos_ids, ghp, gwp, qnw, knw, Qb, Kb, Vt);

  hipFuncSetAttribute((const void*)attn_kernel,
                      hipFuncAttributeMaxDynamicSharedMemorySize, DYNLDS);
  attn_kernel<<<B_ * H_ * NQT, 512, DYNLDS, stream>>>(Qb, Kb, Vt, ctx, attn_out);

  gemm_bt<<<65 * 6, 256, 0, stream>>>(ctx, WoT, out0, B_ * S_, D_, D_);
}

// Round 8
// 335.863 us; speedup vs baseline: 1.5381x; 1.0124x over previous
//
#include <hip/hip_runtime.h>
#include <hip/hip_fp16.h>

#define B_ 8
#define S_ 1025
#define D_ 768
#define H_ 12
#define KV_ 4
#define HD_ 64
#define NREP 3
#define SCALE_ 0.125f
#define EPS_ 1e-6f
#define SKP 1088   // padded key count (17*64)
#define HSS 1092   // LDS fp16 score row stride in halfs (2184 B)
#define QBLK 16    // q-rows per block
#define NQT 65     // ceil(1025/16)
#define DYNLDS 34944  // 16*2184 bytes; P rows live inside score rows (see PROW)

// bf16 P row r lives INSIDE fp16 score row r's footprint:
// byte base = 2184*r + 8*(r&1)  (16B-aligned; 2176B P row fits 2184B score row).
// -> P row r aliases ONLY fp16 row r => same-wave read-then-write, race-free.
#define PROW(r) ((r) * HSS + 4 * ((r) & 1))   // in ushorts

typedef __attribute__((ext_vector_type(8))) short bf16x8;
typedef __attribute__((ext_vector_type(4))) float f32x4;

__device__ __forceinline__ unsigned short f2bf(float f) {
  unsigned int u = __builtin_bit_cast(unsigned int, f);
  return (unsigned short)((u + 0x7FFFu + ((u >> 16) & 1u)) >> 16);
}
__device__ __forceinline__ unsigned int pk2(float a, float b) {
  return (unsigned int)f2bf(a) | ((unsigned int)f2bf(b) << 16);
}

// Raw workgroup barrier that does NOT drain vmcnt: global (nontemporal) stores
// issued before it stay in flight. Only LDS ordering (lgkmcnt) is enforced.
__device__ __forceinline__ void barrier_lgkm() {
  __builtin_amdgcn_sched_barrier(0);
  asm volatile("s_waitcnt lgkmcnt(0)" ::: "memory");
  __builtin_amdgcn_s_barrier();
  __builtin_amdgcn_sched_barrier(0);
}

// ---------------- casts ----------------
__global__ __launch_bounds__(256) void cast_x_kernel(const float* __restrict__ x,
                                                     unsigned short* __restrict__ xb, int n4) {
  int i = blockIdx.x * 256 + threadIdx.x;
  if (i >= n4) return;
  f32x4 v = *(const f32x4*)(x + (size_t)i * 4);
  uint2 o;
  o.x = pk2(v[0], v[1]);
  o.y = pk2(v[2], v[3]);
  *(uint2*)(xb + (size_t)i * 4) = o;
}

__global__ __launch_bounds__(256) void cast_wqkv_kernel(const float* __restrict__ Wq,
    const float* __restrict__ Wk, const float* __restrict__ Wv,
    unsigned short* __restrict__ WT) {
  int idx = blockIdx.x * 256 + threadIdx.x;  // = n*768 + k
  int n = idx / D_, k = idx % D_;
  float v;
  if (n < 768)       v = Wq[(size_t)k * 768 + n];
  else if (n < 1024) v = Wk[(size_t)k * 256 + (n - 768)];
  else               v = Wv[(size_t)k * 256 + (n - 1024)];
  WT[idx] = f2bf(v);
}

__global__ __launch_bounds__(256) void cast_wo_kernel(const float* __restrict__ Wo,
                                                      unsigned short* __restrict__ WT) {
  int idx = blockIdx.x * 256 + threadIdx.x;  // = n*768 + k
  int n = idx / D_, k = idx % D_;
  WT[idx] = f2bf(Wo[(size_t)k * D_ + n]);
}

// ---------------- GEMM: C[M][N] fp32 = A[M][K] bf16 @ BT[N][K] bf16 ----------------
#define BM 128
#define BN 128
#define BK 32
#define LSTR 40   // padded LDS row stride (ushorts)
__global__ __launch_bounds__(256) void gemm_bt(const unsigned short* __restrict__ A,
    const unsigned short* __restrict__ BT, float* __restrict__ C, int M, int N, int K) {
  __shared__ unsigned short As[BM * LSTR];
  __shared__ unsigned short Bs[BN * LSTR];
  const int nMt = (M + BM - 1) / BM;
  const int tm = blockIdx.x % nMt;
  const int tn = blockIdx.x / nMt;
  const int row0 = tm * BM, col0 = tn * BN;
  const int tid = threadIdx.x;
  const int l = tid & 63, w = tid >> 6;
  const int wr = (w >> 1) * 64, wc = (w & 1) * 64;
  const int lr = l & 15, lk = (l >> 4) * 8;
  f32x4 acc[4][4] = {};
  for (int kt = 0; kt < K; kt += BK) {
    __syncthreads();
#pragma unroll
    for (int i = 0; i < 2; ++i) {
      int c = tid + i * 256;
      int r = c >> 2;
      int ce = (c & 3) * 8;
      int gr = row0 + r; gr = gr < M ? gr : M - 1;
      bf16x8 va = *(const bf16x8*)(A + (size_t)gr * K + kt + ce);
      *(bf16x8*)&As[r * LSTR + ce] = va;
      bf16x8 vb = *(const bf16x8*)(BT + (size_t)(col0 + r) * K + kt + ce);
      *(bf16x8*)&Bs[r * LSTR + ce] = vb;
    }
    __syncthreads();
    bf16x8 af[4], bfr[4];
#pragma unroll
    for (int m = 0; m < 4; ++m)
      af[m] = *(const bf16x8*)&As[(wr + m * 16 + lr) * LSTR + lk];
#pragma unroll
    for (int n = 0; n < 4; ++n)
      bfr[n] = *(const bf16x8*)&Bs[(wc + n * 16 + lr) * LSTR + lk];
#pragma unroll
    for (int m = 0; m < 4; ++m)
#pragma unroll
      for (int n = 0; n < 4; ++n)
        acc[m][n] = __builtin_amdgcn_mfma_f32_16x16x32_bf16(af[m], bfr[n], acc[m][n], 0, 0, 0);
  }
  const int orow = (l >> 4) * 4;
#pragma unroll
  for (int m = 0; m < 4; ++m)
#pragma unroll
    for (int n = 0; n < 4; ++n)
#pragma unroll
      for (int r = 0; r < 4; ++r) {
        int row = row0 + wr + m * 16 + orow + r;
        int col = col0 + wc + n * 16 + lr;
        if (row < M) C[(size_t)row * N + col] = acc[m][n][r];
      }
}

// ---------------- QKV epilogue: rmsnorm + rope + layouts (+ V pad zeroing) ----------------
__global__ __launch_bounds__(256) void qkv_epilogue(const float* __restrict__ QKV,
    const int* __restrict__ pos_ids, const int* __restrict__ ghp, const int* __restrict__ gwp,
    const float* __restrict__ qw, const float* __restrict__ kw,
    unsigned short* __restrict__ Qb, unsigned short* __restrict__ Kb,
    unsigned short* __restrict__ Vt) {
  // zero Vt's key-pad region [1025,1088) once (blocks 0..31, one KV plane each)
  if (blockIdx.x < B_ * KV_) {
    unsigned short* vp = Vt + (size_t)blockIdx.x * 64 * SKP;
    for (int idx = threadIdx.x; idx < 64 * 63; idx += 256) {
      int d = idx / 63, s = S_ + idx % 63;
      vp[d * SKP + s] = 0;
    }
  }
  int tok = blockIdx.x * 4 + (threadIdx.x >> 6);
  int l = threadIdx.x & 63;
  if (tok >= B_ * S_) return;
  int b = tok / S_, s = tok % S_;
  const float* rowp = QKV + (size_t)tok * 1280;
  bool rot = (s > 0);
  float cs = 1.f, sn = 0.f;
  if (rot) {
    int gh = ghp[0], gw = gwp[0];
    int pos = pos_ids[tok];
    int hi = (pos / gw) % gh;
    int wi = pos % gw;
    int pi = l >> 1;
    int j = pi < 16 ? pi : pi - 16;
    float invf = exp2f(-(float)j * (13.287712379549449f / 16.f)); // 10000^(-j/16)
    float ang = (pi < 16 ? (float)hi : (float)wi) * invf;
    cs = cosf(ang); sn = sinf(ang);
  }
#pragma unroll
  for (int h = 0; h < H_; ++h) {
    float x = rowp[h * 64 + l];
    float ss = x * x;
    for (int off = 32; off; off >>= 1) ss += __shfl_xor(ss, off);
    float xn = x * rsqrtf(ss * (1.f / 64.f) + EPS_) * qw[l];
    float o = xn;
    if (rot) {
      float p = __shfl_xor(xn, 1);
      o = (l & 1) ? (p * sn + xn * cs) : (xn * cs - p * sn);
    }
    o *= SCALE_;
    Qb[((size_t)(b * H_ + h) * S_ + s) * 64 + l] = f2bf(o);
  }
#pragma unroll
  for (int h = 0; h < KV_; ++h) {
    float x = rowp[768 + h * 64 + l];
    float ss = x * x;
    for (int off = 32; off; off >>= 1) ss += __shfl_xor(ss, off);
    float xn = x * rsqrtf(ss * (1.f / 64.f) + EPS_) * kw[l];
    float o = xn;
    if (rot) {
      float p = __shfl_xor(xn, 1);
      o = (l & 1) ? (p * sn + xn * cs) : (xn * cs - p * sn);
    }
    Kb[((size_t)(b * KV_ + h) * S_ + s) * 64 + l] = f2bf(o);
    float v = rowp[1024 + h * 64 + l];
    Vt[((size_t)(b * KV_ + h) * 64 + l) * SKP + s] = f2bf(v);
  }
}

// ---------------- fused attention ----------------
// block = (b, h, 16 q-rows); 8 waves (512 thr); fp16 scores, 34.1KB dyn LDS -> 4 blk/CU.
// Barriers are raw s_barrier + lgkmcnt(0): nontemporal attn stores issued in phase 2
// stay in flight across PV/ctx and drain overlapped with compute.
__global__ __launch_bounds__(512, 8) void attn_kernel(const unsigned short* __restrict__ Qb,
    const unsigned short* __restrict__ Kb, const unsigned short* __restrict__ Vt,
    unsigned short* __restrict__ ctx, float* __restrict__ attn_out) {
  extern __shared__ unsigned short Ush[];   // fp16 scores [16][HSS]; bf16 P aliased per PROW()
  __shared__ float partial[4][64][4];
  // bijective XCD swizzle: 6240 blocks = 8 * 780
  int bid = blockIdx.x;
  int swz = (bid & 7) * 780 + (bid >> 3);
  int qt = swz % NQT;
  int h = (swz / NQT) % H_;
  int b = swz / (NQT * H_);
  int kvh = h / NREP;
  int q0 = qt * QBLK;
  int tid = threadIdx.x;
  int l = tid & 63, w = tid >> 6;          // w in [0,8)
  int lr = l & 15, lk = (l >> 4) * 8;

  const unsigned short* Qbase = Qb + (size_t)(b * H_ + h) * S_ * 64;
  const unsigned short* Kbase = Kb + (size_t)(b * KV_ + kvh) * S_ * 64;
  const unsigned short* Vbase = Vt + (size_t)(b * KV_ + kvh) * 64 * SKP;

  // Q fragments (scale pre-folded)
  int qrow = q0 + lr; if (qrow >= S_) qrow = S_ - 1;
  bf16x8 qf0 = *(const bf16x8*)(Qbase + (size_t)qrow * 64 + lk);
  bf16x8 qf1 = *(const bf16x8*)(Qbase + (size_t)qrow * 64 + 32 + lk);

  // Phase 1: QK^T -> fp16 scores in LDS. keys t*128 + w*16; t=8 only waves 0-3.
  {
    const int kcol = w * 16 + lr;
    const int nT = (w < 4) ? 9 : 8;
    const unsigned short* kp = Kbase + (size_t)kcol * 64;   // t=0: kcol<128 valid
    bf16x8 kf0 = *(const bf16x8*)(kp + lk);
    bf16x8 kf1 = *(const bf16x8*)(kp + 32 + lk);
    for (int t = 0; t < nT; ++t) {
      bf16x8 nf0 = kf0, nf1 = kf1;
      if (t + 1 < nT) {
        int kr = (t + 1) * 128 + kcol; if (kr >= S_) kr = S_ - 1;
        const unsigned short* np = Kbase + (size_t)kr * 64;
        nf0 = *(const bf16x8*)(np + lk);
        nf1 = *(const bf16x8*)(np + 32 + lk);
      }
      f32x4 acc = {};
      acc = __builtin_amdgcn_mfma_f32_16x16x32_bf16(qf0, kf0, acc, 0, 0, 0);
      acc = __builtin_amdgcn_mfma_f32_16x16x32_bf16(qf1, kf1, acc, 0, 0, 0);
      int col = t * 128 + kcol;            // <= 1087
      int rowb = (l >> 4) * 4;
#pragma unroll
      for (int r = 0; r < 4; ++r)
        Ush[(size_t)(rowb + r) * HSS + col] =
            __builtin_bit_cast(unsigned short, __float2half(acc[r]));
      kf0 = nf0; kf1 = nf1;
    }
  }
  barrier_lgkm();                          // B1

  // Phase 2: softmax rows {w, w+8}; NT fp32 attn stores issued here (never waited on);
  // normalized bf16 P written to LDS at PROW(rowi) — strictly inside fp16 row rowi's
  // footprint, so the only alias is same-row, ordered within this wave (reads first).
#pragma unroll
  for (int rr = 0; rr < 2; ++rr) {
    int rowi = w + rr * 8;
    int q = q0 + rowi;
    const unsigned short* Hrow = Ush + (size_t)rowi * HSS;
    float f[17];
    float mx = -1e30f;
#pragma unroll
    for (int i = 0; i < 17; ++i) {
      int key = l + i * 64;
      float v = (key < S_) ? __half2float(__builtin_bit_cast(__half, Hrow[key])) : -1e30f;
      f[i] = v;
      mx = fmaxf(mx, v);
    }
    for (int off = 32; off; off >>= 1) mx = fmaxf(mx, __shfl_xor(mx, off));
    float sum = 0.f;
#pragma unroll
    for (int i = 0; i < 17; ++i) {
      float e = __expf(f[i] - mx);
      f[i] = e; sum += e;
    }
    for (int off = 32; off; off >>= 1) sum += __shfl_xor(sum, off);
    float inv = 1.f / sum;
#pragma unroll
    for (int i = 0; i < 17; ++i) f[i] *= inv;   // pads are exp(-huge)=0 already
    if (q < S_) {
      float* gout = attn_out + ((size_t)(b * H_ + h) * S_ + q) * S_;
#pragma unroll
      for (int i = 0; i < 16; ++i)
        __builtin_nontemporal_store(f[i], gout + l + i * 64);
      if (l == 0) __builtin_nontemporal_store(f[16], gout + 1024);
    }
    unsigned short* Prow = Ush + PROW(rowi);
#pragma unroll
    for (int i = 0; i < 17; ++i) {
      int key = l + i * 64;
      Prow[key] = f2bf((key < S_) ? f[i] : 0.f);  // zero pads for PV
    }
  }
  barrier_lgkm();                          // B2: P complete -> PV may read

  // Phase 3: PV. wave w: d-block (w&3)*16, key-half (w>>2)*544; 17 kc steps of 32.
  f32x4 accv = {};
  {
    const int d0 = (w & 3) * 16;
    const int kh = (w >> 2) * 544;
    const int prow = PROW(lr);
    const unsigned short* vb = Vbase + (size_t)(d0 + lr) * SKP + kh;
#pragma unroll 4
    for (int kc = 0; kc < 17; ++kc) {
      bf16x8 pa = *(const bf16x8*)&Ush[prow + kh + kc * 32 + lk];
      bf16x8 vf = *(const bf16x8*)(vb + kc * 32 + lk);
      accv = __builtin_amdgcn_mfma_f32_16x16x32_bf16(pa, vf, accv, 0, 0, 0);
    }
  }
  if (w >= 4) *(f32x4*)partial[w - 4][l] = accv;
  barrier_lgkm();                          // B3
  if (w < 4) {
    accv += *(const f32x4*)partial[w][l];
    int rowb = (l >> 4) * 4;
    int d0 = (w & 3) * 16;
#pragma unroll
    for (int r = 0; r < 4; ++r) {
      int q = q0 + rowb + r;
      if (q < S_)
        ctx[(size_t)(b * S_ + q) * 768 + h * 64 + d0 + lr] = f2bf(accv[r]);
    }
  }
}

// ---------------- launch ----------------
extern "C" void kernel_launch(void* const* d_in, const int* in_sizes, int n_in,
                              void* d_out, int out_size, void* d_ws, size_t ws_size,
                              hipStream_t stream) {
  const float* hidden = (const float*)d_in[0];
  const int* pos_ids = (const int*)d_in[2];
  const int* ghp = (const int*)d_in[3];
  const int* gwp = (const int*)d_in[4];
  const float* Wq = (const float*)d_in[5];
  const float* Wk = (const float*)d_in[6];
  const float* Wv = (const float*)d_in[7];
  const float* Wo = (const float*)d_in[8];
  const float* qnw = (const float*)d_in[9];
  const float* knw = (const float*)d_in[10];

  char* ws = (char*)d_ws;
  unsigned short* Xb    = (unsigned short*)ws;                   // 12,595,200
  unsigned short* WqkvT = (unsigned short*)(ws + 12595200);      //  1,966,080
  unsigned short* WoT   = (unsigned short*)(ws + 14561280);      //  1,179,648
  float*          QKV   = (float*)(ws + 15740928);               // 41,984,000
  unsigned short* ctx   = (unsigned short*)(ws + 15740928);      // alias (after QKV consumed)
  unsigned short* Qb    = (unsigned short*)(ws + 57724928);      // 12,595,200
  unsigned short* Kb    = (unsigned short*)(ws + 70320128);      //  4,198,400
  unsigned short* Vt    = (unsigned short*)(ws + 74518528);      //  4,456,448

  float* out0 = (float*)d_out;
  float* attn_out = out0 + (size_t)B_ * S_ * D_;

  cast_x_kernel<<<6150, 256, 0, stream>>>(hidden, Xb, 1574400);
  cast_wqkv_kernel<<<3840, 256, 0, stream>>>(Wq, Wk, Wv, WqkvT);
  cast_wo_kernel<<<2304, 256, 0, stream>>>(Wo, WoT);

  gemm_bt<<<65 * 10, 256, 0, stream>>>(Xb, WqkvT, QKV, B_ * S_, 1280, D_);

  qkv_epilogue<<<2050, 256, 0, stream>>>(QKV, pos_ids, ghp, gwp, qnw, knw, Qb, Kb, Vt);

  hipFuncSetAttribute((const void*)attn_kernel,
                      hipFuncAttributeMaxDynamicSharedMemorySize, DYNLDS);
  attn_kernel<<<B_ * H_ * NQT, 512, DYNLDS, stream>>>(Qb, Kb, Vt, ctx, attn_out);

  gemm_bt<<<65 * 6, 256, 0, stream>>>(ctx, WoT, out0, B_ * S_, D_, D_);
}